// Round 16
// baseline (199.855 us; speedup 1.0000x reference)
//
#include <hip/hip_runtime.h>
#include <hip/hip_bf16.h>

#define D_MODEL 1024
#define NHEADS 16
#define DKH 64
#define BATCH 4
#define SEQ 2048
#define MROWS (BATCH*SEQ)                 // 8192
#define BSD ((size_t)MROWS * D_MODEL)     // 8388608 elements
#define WSZ ((size_t)D_MODEL * D_MODEL)   // 1048576 elements
#define LOG2E 1.4426950408889634f
#define NT64 (SEQ/64)                     // 32 KV tiles of 64 keys

typedef __attribute__((ext_vector_type(8)))  short   s16x8;
typedef __attribute__((ext_vector_type(8)))  __bf16  bf16x8;
typedef __attribute__((ext_vector_type(4)))  __bf16  bf16x4;
typedef __attribute__((ext_vector_type(4)))  float   f32x4;
typedef __attribute__((ext_vector_type(16))) float   f32x16;

// XOR swizzle for [N][64]-bf16 tiles (128B row stride)
#define SWZ(row, scol) ((((int)(row)) << 6) + (((int)(scol)) ^ ((((int)(row)) & 7) << 3)))
// XOR swizzle for [N][32]-bf16 tiles (64B row stride)
#define SWZV(row, scol) ((((int)(row)) << 5) + (((int)(scol)) ^ (((((int)(row)) >> 1) & 3) << 3)))

__device__ inline short f2bf(float f) {
    __bf16 h = (__bf16)f;
    short s; __builtin_memcpy(&s, &h, 2); return s;
}

// packed RNE f32x2 -> bf16x2
__device__ inline unsigned pk2(float a, float b) {
    unsigned r;
    asm("v_cvt_pk_bf16_f32 %0, %1, %2" : "=v"(r) : "v"(a), "v"(b));
    return r;
}
__device__ inline bf16x8 mk8(unsigned w0, unsigned w1, unsigned w2, unsigned w3) {
    union { unsigned u[4]; bf16x8 v; } x;
    x.u[0] = w0; x.u[1] = w1; x.u[2] = w2; x.u[3] = w3;
    return x.v;
}

__device__ inline void gl_lds16(const void* g, void* l) {
    __builtin_amdgcn_global_load_lds(
        (const __attribute__((address_space(1))) unsigned*)g,
        (__attribute__((address_space(3))) unsigned*)l, 16, 0, 0);
}

// ---------------------------------------------------------------------------
// f32 -> bf16 conversion, weights only (4 buffers of WSZ). Grid 4*512.
// ---------------------------------------------------------------------------
struct CvtPtrs { const float* src[4]; short* dst[4]; };

__global__ __launch_bounds__(256) void cvt_w(CvtPtrs p)
{
    const int bx = blockIdx.x;
    const int buf = bx >> 9, boff = bx & 511;
    const float* __restrict__ src = p.src[buf];
    short* __restrict__ dst = p.dst[buf];
    const size_t i = ((size_t)boff * 256 + threadIdx.x) * 8;
    const float4 a = *(const float4*)(src + i);
    const float4 b = *(const float4*)(src + i + 4);
    s16x8 v;
    v[0]=f2bf(a.x); v[1]=f2bf(a.y); v[2]=f2bf(a.z); v[3]=f2bf(a.w);
    v[4]=f2bf(b.x); v[5]=f2bf(b.y); v[6]=f2bf(b.z); v[7]=f2bf(b.w);
    *(s16x8*)(dst + i) = v;
}

// ---------------------------------------------------------------------------
// QKV GEMM: A fp32 via global_load_lds into XOR-swizzled f32 LDS; fragments
// convert with v_cvt_pk_bf16_f32. W bf16 via gl_lds, linear LDS.
// launch_bounds(256,3): 3 blocks/CU (LDS 3x48=144KB <= 160) -- the round-15
// profile showed all-low latency-bound (Mfma 18 / VALU 16 / Occ 28) at 2/CU.
// ---------------------------------------------------------------------------
struct QkvArgs {
    const float* A[3]; const short* W[3]; const float* bias[3];
    short* out[3]; float scale[3]; int omode[3];
};

__global__ __launch_bounds__(256, 3) void gemm_qkv(QkvArgs qa)
{
    __shared__ __align__(16) float Af[128 * 64];   // 32 KB
    __shared__ __align__(16) short Bs[128 * 64];   // 16 KB
    const int z   = blockIdx.z;
    const float* __restrict__ A = qa.A[z];
    const short* __restrict__ W = qa.W[z];
    const float* __restrict__ bias = qa.bias[z];
    short* __restrict__ Cout = qa.out[z];
    const float scale = qa.scale[z];
    const int omode = qa.omode[z];

    const int t   = threadIdx.x;
    const int l   = t & 63;
    const int wid = t >> 6;
    const int g   = l >> 4, r16 = l & 15;
    const int wm  = wid >> 1, wn = wid & 1;
    const int bid = blockIdx.x + (blockIdx.y << 3);
    const int swz = (bid & 7) * 64 + (bid >> 3);
    const int n0  = (swz & 7) * 128, m0 = (swz >> 3) * 128;

    f32x4 acc[4][4];
    #pragma unroll
    for (int mi = 0; mi < 4; ++mi)
        #pragma unroll
        for (int ni = 0; ni < 4; ++ni)
            acc[mi][ni] = (f32x4)0.0f;

    const int arow = t >> 4;
    const int acol = (((t & 15) ^ (arow & 7)) << 2);
    const float* Ap = A + (size_t)(m0 + arow) * D_MODEL + acol;
    float* AfW = Af + wid * 256;
    const int brow = t >> 3;
    const int bcol = (t & 7) * 8;
    const short* Wp = W + (size_t)(n0 + brow) * D_MODEL + bcol;
    short* BsW = Bs + wid * 512;

    for (int k0 = 0; k0 < D_MODEL; k0 += 64) {
        #pragma unroll
        for (int p = 0; p < 8; ++p)
            gl_lds16(Ap + (size_t)p * 16 * D_MODEL + k0, AfW + p * 1024);
        #pragma unroll
        for (int p = 0; p < 4; ++p)
            gl_lds16(Wp + (size_t)p * 32 * D_MODEL + k0, BsW + p * 2048);
        __syncthreads();
        #pragma unroll
        for (int kc = 0; kc < 2; ++kc) {
            bf16x8 a[4], b[4];
            #pragma unroll
            for (int mi = 0; mi < 4; ++mi) {
                const int row = wm * 64 + mi * 16 + r16;
                const int rx  = r16 & 7;
                const int c4  = kc * 8 + g * 2;
                const float4 x = *(const float4*)&Af[row * 64 + ((c4 ^ rx) << 2)];
                const float4 y = *(const float4*)&Af[row * 64 + (((c4 + 1) ^ rx) << 2)];
                a[mi] = mk8(pk2(x.x, x.y), pk2(x.z, x.w), pk2(y.x, y.y), pk2(y.z, y.w));
            }
            #pragma unroll
            for (int ni = 0; ni < 4; ++ni)
                b[ni] = *(const bf16x8*)&Bs[(wn * 64 + ni * 16 + r16) * 64 + kc * 32 + g * 8];
            #pragma unroll
            for (int mi = 0; mi < 4; ++mi)
                #pragma unroll
                for (int ni = 0; ni < 4; ++ni)
                    acc[mi][ni] = __builtin_amdgcn_mfma_f32_16x16x32_bf16(a[mi], b[ni], acc[mi][ni], 0, 0, 0);
        }
        __syncthreads();
    }

    #pragma unroll
    for (int mi = 0; mi < 4; ++mi)
        #pragma unroll
        for (int ni = 0; ni < 4; ++ni) {
            const int n  = n0 + wn * 64 + ni * 16 + r16;
            const int mB = m0 + wm * 64 + mi * 16 + g * 4;
            float v[4];
            #pragma unroll
            for (int j = 0; j < 4; ++j)
                v[j] = (acc[mi][ni][j] + bias[n]) * scale;
            if (omode == 1) {
                const size_t base = ((size_t)((mB >> 11) * NHEADS + (n >> 6)) << 11);
                #pragma unroll
                for (int j = 0; j < 4; ++j)
                    Cout[(base + ((mB + j) & 2047)) * DKH + (n & 63)] = f2bf(v[j]);
            } else {
                // Vt: (B,H,DKH,S); 4 consecutive m = consecutive s -> bf16x4
                bf16x4 ov;
                ov[0] = (__bf16)v[0]; ov[1] = (__bf16)v[1];
                ov[2] = (__bf16)v[2]; ov[3] = (__bf16)v[3];
                const size_t row = (size_t)((mB >> 11) * NHEADS + (n >> 6)) * DKH + (n & 63);
                *(bf16x4*)&Cout[row * SEQ + (mB & 2047)] = ov;
            }
        }
}

// ---------------------------------------------------------------------------
// Output GEMM (bf16 A via gl_lds, linear LDS; fp32 flat out). m97 structure.
// ---------------------------------------------------------------------------
__global__ __launch_bounds__(256, 2) void gemm_out(
    const short* __restrict__ A, const short* __restrict__ W,
    const float* __restrict__ bias, float* __restrict__ C)
{
    __shared__ __align__(16) short As[128 * 64];
    __shared__ __align__(16) short Bs[128 * 64];
    const int t   = threadIdx.x;
    const int l   = t & 63;
    const int wid = t >> 6;
    const int g   = l >> 4, r16 = l & 15;
    const int wm  = wid >> 1, wn = wid & 1;
    const int bid = blockIdx.x + (blockIdx.y << 3);
    const int swz = (bid & 7) * 64 + (bid >> 3);
    const int n0  = (swz & 7) * 128, m0 = (swz >> 3) * 128;
    const int srow = t >> 3;
    const int scol = (t & 7) * 8;

    f32x4 acc[4][4];
    #pragma unroll
    for (int mi = 0; mi < 4; ++mi)
        #pragma unroll
        for (int ni = 0; ni < 4; ++ni)
            acc[mi][ni] = (f32x4)0.0f;

    const short* Ap = A + (size_t)(m0 + srow) * D_MODEL + scol;
    const short* Wp = W + (size_t)(n0 + srow) * D_MODEL + scol;
    short* AsW = As + wid * 512;
    short* BsW = Bs + wid * 512;

    for (int k0 = 0; k0 < D_MODEL; k0 += 64) {
        #pragma unroll
        for (int p = 0; p < 4; ++p) {
            gl_lds16(Ap + (size_t)p * 32 * D_MODEL + k0, AsW + p * 2048);
            gl_lds16(Wp + (size_t)p * 32 * D_MODEL + k0, BsW + p * 2048);
        }
        __syncthreads();
        #pragma unroll
        for (int kc = 0; kc < 2; ++kc) {
            bf16x8 a[4], b[4];
            #pragma unroll
            for (int mi = 0; mi < 4; ++mi)
                a[mi] = *(const bf16x8*)&As[(wm * 64 + mi * 16 + r16) * 64 + kc * 32 + g * 8];
            #pragma unroll
            for (int ni = 0; ni < 4; ++ni)
                b[ni] = *(const bf16x8*)&Bs[(wn * 64 + ni * 16 + r16) * 64 + kc * 32 + g * 8];
            #pragma unroll
            for (int mi = 0; mi < 4; ++mi)
                #pragma unroll
                for (int ni = 0; ni < 4; ++ni)
                    acc[mi][ni] = __builtin_amdgcn_mfma_f32_16x16x32_bf16(a[mi], b[ni], acc[mi][ni], 0, 0, 0);
        }
        __syncthreads();
    }

    #pragma unroll
    for (int mi = 0; mi < 4; ++mi)
        #pragma unroll
        for (int ni = 0; ni < 4; ++ni)
            #pragma unroll
            for (int j = 0; j < 4; ++j) {
                const int m = m0 + wm * 64 + mi * 16 + g * 4 + j;
                const int n = n0 + wn * 64 + ni * 16 + r16;
                C[(size_t)m * D_MODEL + n] = acc[mi][ni][j] + bias[n];
            }
}

// ---------------------------------------------------------------------------
// Flash attention, KVBLK=64 (round-15). 32x32x16 MFMA, swapped operands,
// P in registers (T12), fixed-reference softmax (m=0, exp2 domain).
// LDS 64 KB: Q 32K + dbuf 2x(K 8K + V 8K). 64 q-rows/wave; grid 512.
// ---------------------------------------------------------------------------
__global__ __launch_bounds__(256, 2) void attn_mfma(
    const short* __restrict__ Qg, const short* __restrict__ Kg,
    const short* __restrict__ Vtg, short* __restrict__ Ab)
{
    __shared__ __align__(16) short lds[32768];   // 64 KB
    const int t   = threadIdx.x;
    const int l   = t & 63;
    const int wid = t >> 6;
    const int l31 = l & 31, hi = l >> 5;
    const int bid  = blockIdx.x + (blockIdx.y << 3);
    const int swz  = (bid & 7) * 64 + (bid >> 3);
    const int head = swz >> 3, b = head >> 4, h = head & 15;
    const int q0   = (swz & 7) << 8;
    const int wq0  = wid * 64;

    const short* Kbase = Kg  + (size_t)head * SEQ * DKH;
    const short* Vbase = Vtg + (size_t)head * DKH * SEQ;

    const int qrow = t >> 3;
    const int qg8  = ((t & 7) ^ (qrow & 7)) * 8;
    const short* qsrc = Qg + ((size_t)head * SEQ + q0 + qrow) * DKH + qg8;
    const int kr8 = t >> 3;
    const short* ksrc = Kbase + (size_t)kr8 * DKH + (((t & 7) ^ (kr8 & 7)) * 8);
    const int vr4 = t >> 2;
    const short* vsrc = Vbase + (size_t)vr4 * SEQ + (((t & 3) ^ ((vr4 >> 1) & 3)) * 8);

    short* const ldsQ  = &lds[wid * 512];
    short* const ldsKA = &lds[16384 + wid * 512];
    short* const ldsVA = &lds[20480 + wid * 512];
    short* const ldsKB = &lds[24576 + wid * 512];
    short* const ldsVB = &lds[28672 + wid * 512];

    #pragma unroll
    for (int i = 0; i < 8; ++i)
        gl_lds16(qsrc + (size_t)i * 32 * DKH, ldsQ + i * 2048);
    gl_lds16(ksrc,        ldsKA);        gl_lds16(ksrc + 2048, ldsKA + 2048);
    gl_lds16(vsrc,        ldsVA);        gl_lds16(vsrc + 32,   ldsVA + 2048);
    gl_lds16(ksrc + 4096, ldsKB);        gl_lds16(ksrc + 6144, ldsKB + 2048);
    gl_lds16(vsrc + 64,   ldsVB);        gl_lds16(vsrc + 96,   ldsVB + 2048);
    __syncthreads();

    bf16x8 bq0[4], bq1[4];
    #pragma unroll
    for (int kc = 0; kc < 4; ++kc) {
        bq0[kc] = *(const bf16x8*)&lds[SWZ(wq0 + l31,      kc * 16 + hi * 8)];
        bq1[kc] = *(const bf16x8*)&lds[SWZ(wq0 + 32 + l31, kc * 16 + hi * 8)];
    }

    f32x16 o00 = (f32x16)0.0f, o01 = (f32x16)0.0f;
    f32x16 o10 = (f32x16)0.0f, o11 = (f32x16)0.0f;
    float l0 = 0.0f, l1 = 0.0f;

    for (int kt = 0; kt < NT64; ++kt) {
        const int KO = (kt & 1) ? 24576 : 16384;
        const int VO = (kt & 1) ? 28672 : 20480;

        f32x16 s0a = (f32x16)0.0f, s0b = (f32x16)0.0f;
        f32x16 s1a = (f32x16)0.0f, s1b = (f32x16)0.0f;
        __builtin_amdgcn_s_setprio(1);
        #pragma unroll
        for (int kc = 0; kc < 4; ++kc) {
            const bf16x8 ak0 = *(const bf16x8*)&lds[KO + SWZ(l31,      kc * 16 + hi * 8)];
            const bf16x8 ak1 = *(const bf16x8*)&lds[KO + SWZ(32 + l31, kc * 16 + hi * 8)];
            s0a = __builtin_amdgcn_mfma_f32_32x32x16_bf16(ak0, bq0[kc], s0a, 0, 0, 0);
            s1a = __builtin_amdgcn_mfma_f32_32x32x16_bf16(ak0, bq1[kc], s1a, 0, 0, 0);
            s0b = __builtin_amdgcn_mfma_f32_32x32x16_bf16(ak1, bq0[kc], s0b, 0, 0, 0);
            s1b = __builtin_amdgcn_mfma_f32_32x32x16_bf16(ak1, bq1[kc], s1b, 0, 0, 0);
        }
        __builtin_amdgcn_s_setprio(0);

        #pragma unroll
        for (int r = 0; r < 16; ++r) s0a[r] = __builtin_amdgcn_exp2f(s0a[r]);
        #pragma unroll
        for (int r = 0; r < 16; ++r) s0b[r] = __builtin_amdgcn_exp2f(s0b[r]);
        #pragma unroll
        for (int r = 0; r < 16; ++r) s1a[r] = __builtin_amdgcn_exp2f(s1a[r]);
        #pragma unroll
        for (int r = 0; r < 16; ++r) s1b[r] = __builtin_amdgcn_exp2f(s1b[r]);
        {
            const float a0 = ((s0a[0]+s0a[1]) + (s0a[2]+s0a[3])) + ((s0a[4]+s0a[5]) + (s0a[6]+s0a[7]));
            const float a1 = ((s0a[8]+s0a[9]) + (s0a[10]+s0a[11])) + ((s0a[12]+s0a[13]) + (s0a[14]+s0a[15]));
            const float a2 = ((s0b[0]+s0b[1]) + (s0b[2]+s0b[3])) + ((s0b[4]+s0b[5]) + (s0b[6]+s0b[7]));
            const float a3 = ((s0b[8]+s0b[9]) + (s0b[10]+s0b[11])) + ((s0b[12]+s0b[13]) + (s0b[14]+s0b[15]));
            l0 += (a0 + a1) + (a2 + a3);
            const float c0 = ((s1a[0]+s1a[1]) + (s1a[2]+s1a[3])) + ((s1a[4]+s1a[5]) + (s1a[6]+s1a[7]));
            const float c1 = ((s1a[8]+s1a[9]) + (s1a[10]+s1a[11])) + ((s1a[12]+s1a[13]) + (s1a[14]+s1a[15]));
            const float c2 = ((s1b[0]+s1b[1]) + (s1b[2]+s1b[3])) + ((s1b[4]+s1b[5]) + (s1b[6]+s1b[7]));
            const float c3 = ((s1b[8]+s1b[9]) + (s1b[10]+s1b[11])) + ((s1b[12]+s1b[13]) + (s1b[14]+s1b[15]));
            l1 += (c0 + c1) + (c2 + c3);
        }

        // --- k-block a: pack (T12) + PV on V subtile 0 ---
        {
            bf16x8 bp00, bp01, bp10, bp11;
            {
                unsigned a0 = pk2(s0a[0], s0a[1]),  b0 = pk2(s0a[4],  s0a[5]);
                unsigned a1 = pk2(s0a[2], s0a[3]),  b1 = pk2(s0a[6],  s0a[7]);
                asm("v_permlane32_swap_b32 %0, %1" : "+v"(a0), "+v"(b0));
                asm("v_permlane32_swap_b32 %0, %1" : "+v"(a1), "+v"(b1));
                bp00 = mk8(a0, a1, b0, b1);
                unsigned a2 = pk2(s0a[8], s0a[9]),   b2 = pk2(s0a[12], s0a[13]);
                unsigned a3 = pk2(s0a[10], s0a[11]), b3 = pk2(s0a[14], s0a[15]);
                asm("v_permlane32_swap_b32 %0, %1" : "+v"(a2), "+v"(b2));
                asm("v_permlane32_swap_b32 %0, %1" : "+v"(a3), "+v"(b3));
                bp01 = mk8(a2, a3, b2, b3);
            }
            {
                unsigned a0 = pk2(s1a[0], s1a[1]),  b0 = pk2(s1a[4],  s1a[5]);
                unsigned a1 = pk2(s1a[2], s1a[3]),  b1 = pk2(s1a[6],  s1a[7]);
                asm("v_permlane32_swap_b32 %0, %1" : "+v"(a0), "+v"(b0));
                asm("v_permlane32_swap_b32 %0, %1" : "+v"(a1), "+v"(b1));
                bp10 = mk8(a0, a1, b0, b1);
                unsigned a2 = pk2(s1a[8], s1a[9]),   b2 = pk2(s1a[12], s1a[13]);
                unsigned a3 = pk2(s1a[10], s1a[11]), b3 = pk2(s1a[14], s1a[15]);
                asm("v_permlane32_swap_b32 %0, %1" : "+v"(a2), "+v"(b2));
                asm("v_permlane32_swap_b32 %0, %1" : "+v"(a3), "+v"(b3));
                bp11 = mk8(a2, a3, b2, b3);
            }
            __builtin_amdgcn_s_setprio(1);
            const bf16x8 avA0 = *(const bf16x8*)&lds[VO + SWZV(l31,      hi * 8)];
            const bf16x8 avA1 = *(const bf16x8*)&lds[VO + SWZV(32 + l31, hi * 8)];
            o00 = __builtin_amdgcn_mfma_f32_32x32x16_bf16(avA0, bp00, o00, 0, 0, 0);
            o01 = __builtin_amdgcn_mfma_f32_32x32x16_bf16(avA1, bp00, o01, 0, 0, 0);
            o10 = __builtin_amdgcn_mfma_f32_32x32x16_bf16(avA0, bp10, o10, 0, 0, 0);
            o11 = __builtin_amdgcn_mfma_f32_32x32x16_bf16(avA1, bp10, o11, 0, 0, 0);
            const bf16x8 avB0 = *(const bf16x8*)&lds[VO + SWZV(l31,      16 + hi * 8)];
            const bf16x8 avB1 = *(const bf16x8*)&lds[VO + SWZV(32 + l31, 16 + hi * 8)];
            o00 = __builtin_amdgcn_mfma_f32_32x32x16_bf16(avB0, bp01, o00, 0, 0, 0);
            o01 = __builtin_amdgcn_mfma_f32_32x32x16_bf16(avB1, bp01, o01, 0, 0, 0);
            o10 = __builtin_amdgcn_mfma_f32_32x32x16_bf16(avB0, bp11, o10, 0, 0, 0);
            o11 = __builtin_amdgcn_mfma_f32_32x32x16_bf16(avB1, bp11, o11, 0, 0, 0);
            __builtin_amdgcn_s_setprio(0);
        }

        // --- k-block b: pack + PV on V subtile 1 (VO + 2048) ---
        {
            bf16x8 bp00, bp01, bp10, bp11;
            {
                unsigned a0 = pk2(s0b[0], s0b[1]),  b0 = pk2(s0b[4],  s0b[5]);
                unsigned a1 = pk2(s0b[2], s0b[3]),  b1 = pk2(s0b[6],  s0b[7]);
                asm("v_permlane32_swap_b32 %0, %1" : "+v"(a0), "+v"(b0));
                asm("v_permlane32_swap_b32 %0, %1" : "+v"(a1), "+v"(b1));
                bp00 = mk8(a0, a1, b0, b1);
                unsigned a2 = pk2(s0b[8], s0b[9]),   b2 = pk2(s0b[12], s0b[13]);
                unsigned a3 = pk2(s0b[10], s0b[11]), b3 = pk2(s0b[14], s0b[15]);
                asm("v_permlane32_swap_b32 %0, %1" : "+v"(a2), "+v"(b2));
                asm("v_permlane32_swap_b32 %0, %1" : "+v"(a3), "+v"(b3));
                bp01 = mk8(a2, a3, b2, b3);
            }
            {
                unsigned a0 = pk2(s1b[0], s1b[1]),  b0 = pk2(s1b[4],  s1b[5]);
                unsigned a1 = pk2(s1b[2], s1b[3]),  b1 = pk2(s1b[6],  s1b[7]);
                asm("v_permlane32_swap_b32 %0, %1" : "+v"(a0), "+v"(b0));
                asm("v_permlane32_swap_b32 %0, %1" : "+v"(a1), "+v"(b1));
                bp10 = mk8(a0, a1, b0, b1);
                unsigned a2 = pk2(s1b[8], s1b[9]),   b2 = pk2(s1b[12], s1b[13]);
                unsigned a3 = pk2(s1b[10], s1b[11]), b3 = pk2(s1b[14], s1b[15]);
                asm("v_permlane32_swap_b32 %0, %1" : "+v"(a2), "+v"(b2));
                asm("v_permlane32_swap_b32 %0, %1" : "+v"(a3), "+v"(b3));
                bp11 = mk8(a2, a3, b2, b3);
            }
            __builtin_amdgcn_s_setprio(1);
            const int VO1 = VO + 2048;
            const bf16x8 avA0 = *(const bf16x8*)&lds[VO1 + SWZV(l31,      hi * 8)];
            const bf16x8 avA1 = *(const bf16x8*)&lds[VO1 + SWZV(32 + l31, hi * 8)];
            o00 = __builtin_amdgcn_mfma_f32_32x32x16_bf16(avA0, bp00, o00, 0, 0, 0);
            o01 = __builtin_amdgcn_mfma_f32_32x32x16_bf16(avA1, bp00, o01, 0, 0, 0);
            o10 = __builtin_amdgcn_mfma_f32_32x32x16_bf16(avA0, bp10, o10, 0, 0, 0);
            o11 = __builtin_amdgcn_mfma_f32_32x32x16_bf16(avA1, bp10, o11, 0, 0, 0);
            const bf16x8 avB0 = *(const bf16x8*)&lds[VO1 + SWZV(l31,      16 + hi * 8)];
            const bf16x8 avB1 = *(const bf16x8*)&lds[VO1 + SWZV(32 + l31, 16 + hi * 8)];
            o00 = __builtin_amdgcn_mfma_f32_32x32x16_bf16(avB0, bp01, o00, 0, 0, 0);
            o01 = __builtin_amdgcn_mfma_f32_32x32x16_bf16(avB1, bp01, o01, 0, 0, 0);
            o10 = __builtin_amdgcn_mfma_f32_32x32x16_bf16(avB0, bp11, o10, 0, 0, 0);
            o11 = __builtin_amdgcn_mfma_f32_32x32x16_bf16(avB1, bp11, o11, 0, 0, 0);
            __builtin_amdgcn_s_setprio(0);
        }

        __syncthreads();
        if (kt + 2 < NT64) {
            short* const kdst = (kt & 1) ? ldsKB : ldsKA;
            short* const vdst = (kt & 1) ? ldsVB : ldsVA;
            const size_t ko = (size_t)(kt + 2) * 4096;
            const int    vo = (kt + 2) * 64;
            gl_lds16(ksrc + ko,        kdst);
            gl_lds16(ksrc + ko + 2048, kdst + 2048);
            gl_lds16(vsrc + vo,        vdst);
            gl_lds16(vsrc + vo + 32,   vdst + 2048);
        }
    }

    #pragma unroll
    for (int qb = 0; qb < 2; ++qb) {
        const float lr = qb ? l1 : l0;
        const f32x16 oa = qb ? o10 : o00;
        const f32x16 ob = qb ? o11 : o01;
        const float lt = lr + __shfl_xor(lr, 32);
        const float inv = 1.0f / lt;
        const int q = q0 + wq0 + qb * 32 + l31;
        short* Op = Ab + ((size_t)b * SEQ + q) * D_MODEL + h * DKH;
        #pragma unroll
        for (int rr = 0; rr < 4; ++rr) {
            bf16x4 ov;
            ov[0] = (__bf16)(oa[rr*4+0] * inv); ov[1] = (__bf16)(oa[rr*4+1] * inv);
            ov[2] = (__bf16)(oa[rr*4+2] * inv); ov[3] = (__bf16)(oa[rr*4+3] * inv);
            *(bf16x4*)&Op[rr * 8 + hi * 4] = ov;
            bf16x4 ow;
            ow[0] = (__bf16)(ob[rr*4+0] * inv); ow[1] = (__bf16)(ob[rr*4+1] * inv);
            ow[2] = (__bf16)(ob[rr*4+2] * inv); ow[3] = (__bf16)(ob[rr*4+3] * inv);
            *(bf16x4*)&Op[32 + rr * 8 + hi * 4] = ow;
        }
    }
}

extern "C" void kernel_launch(void* const* d_in, const int* in_sizes, int n_in,
                              void* d_out, int out_size, void* d_ws, size_t ws_size,
                              hipStream_t stream) {
    const float* q_in = (const float*)d_in[0];
    const float* k_in = (const float*)d_in[1];
    const float* v_in = (const float*)d_in[2];
    const float* w_q  = (const float*)d_in[3];
    const float* b_q  = (const float*)d_in[4];
    const float* w_k  = (const float*)d_in[5];
    const float* b_k  = (const float*)d_in[6];
    const float* w_v  = (const float*)d_in[7];
    const float* b_v  = (const float*)d_in[8];
    const float* w_o  = (const float*)d_in[9];
    const float* b_o  = (const float*)d_in[10];
    float* out = (float*)d_out;

    short* ws = (short*)d_ws;
    short* Wq = ws;                   // bf16 weights
    short* Wk = Wq + WSZ;
    short* Wv = Wk + WSZ;
    short* Wo = Wv + WSZ;
    short* Qb = ws + 4 * WSZ;         // (B,H,S,64) bf16, pre-scaled
    short* Kb = Qb + BSD;             // (B,H,S,64) bf16
    short* Vt = Kb + BSD;             // (B,H,64,S) bf16 -- direct from gemm
    short* Ab = Vt + BSD;             // (B,S,D) bf16 attn output

    dim3 blk(256);

    CvtPtrs cp;
    cp.src[0] = w_q; cp.dst[0] = Wq;
    cp.src[1] = w_k; cp.dst[1] = Wk;
    cp.src[2] = w_v; cp.dst[2] = Wv;
    cp.src[3] = w_o; cp.dst[3] = Wo;
    cvt_w<<<dim3(4 * 512), blk, 0, stream>>>(cp);

    QkvArgs qa;
    qa.A[0] = q_in; qa.W[0] = Wq; qa.bias[0] = b_q; qa.out[0] = Qb; qa.scale[0] = 0.125f * LOG2E; qa.omode[0] = 1;
    qa.A[1] = k_in; qa.W[1] = Wk; qa.bias[1] = b_k; qa.out[1] = Kb; qa.scale[1] = 1.0f;           qa.omode[1] = 1;
    qa.A[2] = v_in; qa.W[2] = Wv; qa.bias[2] = b_v; qa.out[2] = Vt; qa.scale[2] = 1.0f;           qa.omode[2] = 2;
    gemm_qkv<<<dim3(D_MODEL / 128, MROWS / 128, 3), blk, 0, stream>>>(qa);

    attn_mfma<<<dim3(SEQ / 256, BATCH * NHEADS), blk, 0, stream>>>(Qb, Kb, Vt, Ab);

    gemm_out<<<dim3(D_MODEL / 128, MROWS / 128), blk, 0, stream>>>(Ab, Wo, b_o, out);
}

// Round 17
// 192.255 us; speedup vs baseline: 1.0395x; 1.0395x over previous
//
#include <hip/hip_runtime.h>
#include <hip/hip_bf16.h>

#define D_MODEL 1024
#define NHEADS 16
#define DKH 64
#define BATCH 4
#define SEQ 2048
#define MROWS (BATCH*SEQ)                 // 8192
#define BSD ((size_t)MROWS * D_MODEL)     // 8388608 elements
#define WSZ ((size_t)D_MODEL * D_MODEL)   // 1048576 elements
#define LOG2E 1.4426950408889634f
#define NT64 (SEQ/64)                     // 32 KV tiles of 64 keys

typedef __attribute__((ext_vector_type(8)))  short   s16x8;
typedef __attribute__((ext_vector_type(8)))  __bf16  bf16x8;
typedef __attribute__((ext_vector_type(4)))  __bf16  bf16x4;
typedef __attribute__((ext_vector_type(4)))  float   f32x4;
typedef __attribute__((ext_vector_type(16))) float   f32x16;

// XOR swizzle for [N][64]-bf16 tiles (128B row stride)
#define SWZ(row, scol) ((((int)(row)) << 6) + (((int)(scol)) ^ ((((int)(row)) & 7) << 3)))
// XOR swizzle for [N][32]-bf16 tiles (64B row stride)
#define SWZV(row, scol) ((((int)(row)) << 5) + (((int)(scol)) ^ (((((int)(row)) >> 1) & 3) << 3)))

__device__ inline short f2bf(float f) {
    __bf16 h = (__bf16)f;
    short s; __builtin_memcpy(&s, &h, 2); return s;
}

// packed RNE f32x2 -> bf16x2
__device__ inline unsigned pk2(float a, float b) {
    unsigned r;
    asm("v_cvt_pk_bf16_f32 %0, %1, %2" : "=v"(r) : "v"(a), "v"(b));
    return r;
}
__device__ inline bf16x8 mk8(unsigned w0, unsigned w1, unsigned w2, unsigned w3) {
    union { unsigned u[4]; bf16x8 v; } x;
    x.u[0] = w0; x.u[1] = w1; x.u[2] = w2; x.u[3] = w3;
    return x.v;
}

__device__ inline void gl_lds16(const void* g, void* l) {
    __builtin_amdgcn_global_load_lds(
        (const __attribute__((address_space(1))) unsigned*)g,
        (__attribute__((address_space(3))) unsigned*)l, 16, 0, 0);
}

// ---------------------------------------------------------------------------
// f32 -> bf16 conversion, weights only (4 buffers of WSZ). Grid 4*512.
// ---------------------------------------------------------------------------
struct CvtPtrs { const float* src[4]; short* dst[4]; };

__global__ __launch_bounds__(256) void cvt_w(CvtPtrs p)
{
    const int bx = blockIdx.x;
    const int buf = bx >> 9, boff = bx & 511;
    const float* __restrict__ src = p.src[buf];
    short* __restrict__ dst = p.dst[buf];
    const size_t i = ((size_t)boff * 256 + threadIdx.x) * 8;
    const float4 a = *(const float4*)(src + i);
    const float4 b = *(const float4*)(src + i + 4);
    s16x8 v;
    v[0]=f2bf(a.x); v[1]=f2bf(a.y); v[2]=f2bf(a.z); v[3]=f2bf(a.w);
    v[4]=f2bf(b.x); v[5]=f2bf(b.y); v[6]=f2bf(b.z); v[7]=f2bf(b.w);
    *(s16x8*)(dst + i) = v;
}

// ---------------------------------------------------------------------------
// QKV GEMM (round-14 best): A fp32 via global_load_lds into XOR-swizzled f32
// LDS; fragments convert with v_cvt_pk_bf16_f32. W bf16 via gl_lds.
// launch_bounds(256,2) -- the (256,3) variant was a measured null (r16).
// ---------------------------------------------------------------------------
struct QkvArgs {
    const float* A[3]; const short* W[3]; const float* bias[3];
    short* out[3]; float scale[3]; int omode[3];
};

__global__ __launch_bounds__(256, 2) void gemm_qkv(QkvArgs qa)
{
    __shared__ __align__(16) float Af[128 * 64];   // 32 KB
    __shared__ __align__(16) short Bs[128 * 64];   // 16 KB
    const int z   = blockIdx.z;
    const float* __restrict__ A = qa.A[z];
    const short* __restrict__ W = qa.W[z];
    const float* __restrict__ bias = qa.bias[z];
    short* __restrict__ Cout = qa.out[z];
    const float scale = qa.scale[z];
    const int omode = qa.omode[z];

    const int t   = threadIdx.x;
    const int l   = t & 63;
    const int wid = t >> 6;
    const int g   = l >> 4, r16 = l & 15;
    const int wm  = wid >> 1, wn = wid & 1;
    const int bid = blockIdx.x + (blockIdx.y << 3);
    const int swz = (bid & 7) * 64 + (bid >> 3);
    const int n0  = (swz & 7) * 128, m0 = (swz >> 3) * 128;

    f32x4 acc[4][4];
    #pragma unroll
    for (int mi = 0; mi < 4; ++mi)
        #pragma unroll
        for (int ni = 0; ni < 4; ++ni)
            acc[mi][ni] = (f32x4)0.0f;

    const int arow = t >> 4;
    const int acol = (((t & 15) ^ (arow & 7)) << 2);
    const float* Ap = A + (size_t)(m0 + arow) * D_MODEL + acol;
    float* AfW = Af + wid * 256;
    const int brow = t >> 3;
    const int bcol = (t & 7) * 8;
    const short* Wp = W + (size_t)(n0 + brow) * D_MODEL + bcol;
    short* BsW = Bs + wid * 512;

    for (int k0 = 0; k0 < D_MODEL; k0 += 64) {
        #pragma unroll
        for (int p = 0; p < 8; ++p)
            gl_lds16(Ap + (size_t)p * 16 * D_MODEL + k0, AfW + p * 1024);
        #pragma unroll
        for (int p = 0; p < 4; ++p)
            gl_lds16(Wp + (size_t)p * 32 * D_MODEL + k0, BsW + p * 2048);
        __syncthreads();
        #pragma unroll
        for (int kc = 0; kc < 2; ++kc) {
            bf16x8 a[4], b[4];
            #pragma unroll
            for (int mi = 0; mi < 4; ++mi) {
                const int row = wm * 64 + mi * 16 + r16;
                const int rx  = r16 & 7;
                const int c4  = kc * 8 + g * 2;
                const float4 x = *(const float4*)&Af[row * 64 + ((c4 ^ rx) << 2)];
                const float4 y = *(const float4*)&Af[row * 64 + (((c4 + 1) ^ rx) << 2)];
                a[mi] = mk8(pk2(x.x, x.y), pk2(x.z, x.w), pk2(y.x, y.y), pk2(y.z, y.w));
            }
            #pragma unroll
            for (int ni = 0; ni < 4; ++ni)
                b[ni] = *(const bf16x8*)&Bs[(wn * 64 + ni * 16 + r16) * 64 + kc * 32 + g * 8];
            #pragma unroll
            for (int mi = 0; mi < 4; ++mi)
                #pragma unroll
                for (int ni = 0; ni < 4; ++ni)
                    acc[mi][ni] = __builtin_amdgcn_mfma_f32_16x16x32_bf16(a[mi], b[ni], acc[mi][ni], 0, 0, 0);
        }
        __syncthreads();
    }

    #pragma unroll
    for (int mi = 0; mi < 4; ++mi)
        #pragma unroll
        for (int ni = 0; ni < 4; ++ni) {
            const int n  = n0 + wn * 64 + ni * 16 + r16;
            const int mB = m0 + wm * 64 + mi * 16 + g * 4;
            float v[4];
            #pragma unroll
            for (int j = 0; j < 4; ++j)
                v[j] = (acc[mi][ni][j] + bias[n]) * scale;
            if (omode == 1) {
                const size_t base = ((size_t)((mB >> 11) * NHEADS + (n >> 6)) << 11);
                #pragma unroll
                for (int j = 0; j < 4; ++j)
                    Cout[(base + ((mB + j) & 2047)) * DKH + (n & 63)] = f2bf(v[j]);
            } else {
                // Vt: (B,H,DKH,S); 4 consecutive m = consecutive s -> bf16x4
                bf16x4 ov;
                ov[0] = (__bf16)v[0]; ov[1] = (__bf16)v[1];
                ov[2] = (__bf16)v[2]; ov[3] = (__bf16)v[3];
                const size_t row = (size_t)((mB >> 11) * NHEADS + (n >> 6)) * DKH + (n & 63);
                *(bf16x4*)&Cout[row * SEQ + (mB & 2047)] = ov;
            }
        }
}

// ---------------------------------------------------------------------------
// Output GEMM (bf16 A via gl_lds, linear LDS; fp32 flat out). m97 structure.
// ---------------------------------------------------------------------------
__global__ __launch_bounds__(256, 2) void gemm_out(
    const short* __restrict__ A, const short* __restrict__ W,
    const float* __restrict__ bias, float* __restrict__ C)
{
    __shared__ __align__(16) short As[128 * 64];
    __shared__ __align__(16) short Bs[128 * 64];
    const int t   = threadIdx.x;
    const int l   = t & 63;
    const int wid = t >> 6;
    const int g   = l >> 4, r16 = l & 15;
    const int wm  = wid >> 1, wn = wid & 1;
    const int bid = blockIdx.x + (blockIdx.y << 3);
    const int swz = (bid & 7) * 64 + (bid >> 3);
    const int n0  = (swz & 7) * 128, m0 = (swz >> 3) * 128;
    const int srow = t >> 3;
    const int scol = (t & 7) * 8;

    f32x4 acc[4][4];
    #pragma unroll
    for (int mi = 0; mi < 4; ++mi)
        #pragma unroll
        for (int ni = 0; ni < 4; ++ni)
            acc[mi][ni] = (f32x4)0.0f;

    const short* Ap = A + (size_t)(m0 + srow) * D_MODEL + scol;
    const short* Wp = W + (size_t)(n0 + srow) * D_MODEL + scol;
    short* AsW = As + wid * 512;
    short* BsW = Bs + wid * 512;

    for (int k0 = 0; k0 < D_MODEL; k0 += 64) {
        #pragma unroll
        for (int p = 0; p < 4; ++p) {
            gl_lds16(Ap + (size_t)p * 32 * D_MODEL + k0, AsW + p * 2048);
            gl_lds16(Wp + (size_t)p * 32 * D_MODEL + k0, BsW + p * 2048);
        }
        __syncthreads();
        #pragma unroll
        for (int kc = 0; kc < 2; ++kc) {
            bf16x8 a[4], b[4];
            #pragma unroll
            for (int mi = 0; mi < 4; ++mi)
                a[mi] = *(const bf16x8*)&As[(wm * 64 + mi * 16 + r16) * 64 + kc * 32 + g * 8];
            #pragma unroll
            for (int ni = 0; ni < 4; ++ni)
                b[ni] = *(const bf16x8*)&Bs[(wn * 64 + ni * 16 + r16) * 64 + kc * 32 + g * 8];
            #pragma unroll
            for (int mi = 0; mi < 4; ++mi)
                #pragma unroll
                for (int ni = 0; ni < 4; ++ni)
                    acc[mi][ni] = __builtin_amdgcn_mfma_f32_16x16x32_bf16(a[mi], b[ni], acc[mi][ni], 0, 0, 0);
        }
        __syncthreads();
    }

    #pragma unroll
    for (int mi = 0; mi < 4; ++mi)
        #pragma unroll
        for (int ni = 0; ni < 4; ++ni)
            #pragma unroll
            for (int j = 0; j < 4; ++j) {
                const int m = m0 + wm * 64 + mi * 16 + g * 4 + j;
                const int n = n0 + wn * 64 + ni * 16 + r16;
                C[(size_t)m * D_MODEL + n] = acc[mi][ni][j] + bias[n];
            }
}

// ---------------------------------------------------------------------------
// Flash attention, KVBLK=64. 32x32x16 MFMA, swapped operands, P in registers
// (T12), fixed-reference softmax (m=0, exp2 domain). LDS 64 KB: Q 32K +
// dbuf 2x(K 8K + V 8K). 64 q-rows/wave; grid 512 = 2 blocks/CU.
// ---------------------------------------------------------------------------
__global__ __launch_bounds__(256, 2) void attn_mfma(
    const short* __restrict__ Qg, const short* __restrict__ Kg,
    const short* __restrict__ Vtg, short* __restrict__ Ab)
{
    __shared__ __align__(16) short lds[32768];   // 64 KB
    const int t   = threadIdx.x;
    const int l   = t & 63;
    const int wid = t >> 6;
    const int l31 = l & 31, hi = l >> 5;
    const int bid  = blockIdx.x + (blockIdx.y << 3);
    const int swz  = (bid & 7) * 64 + (bid >> 3);
    const int head = swz >> 3, b = head >> 4, h = head & 15;
    const int q0   = (swz & 7) << 8;
    const int wq0  = wid * 64;

    const short* Kbase = Kg  + (size_t)head * SEQ * DKH;
    const short* Vbase = Vtg + (size_t)head * DKH * SEQ;

    const int qrow = t >> 3;
    const int qg8  = ((t & 7) ^ (qrow & 7)) * 8;
    const short* qsrc = Qg + ((size_t)head * SEQ + q0 + qrow) * DKH + qg8;
    const int kr8 = t >> 3;
    const short* ksrc = Kbase + (size_t)kr8 * DKH + (((t & 7) ^ (kr8 & 7)) * 8);
    const int vr4 = t >> 2;
    const short* vsrc = Vbase + (size_t)vr4 * SEQ + (((t & 3) ^ ((vr4 >> 1) & 3)) * 8);

    short* const ldsQ  = &lds[wid * 512];
    short* const ldsKA = &lds[16384 + wid * 512];
    short* const ldsVA = &lds[20480 + wid * 512];
    short* const ldsKB = &lds[24576 + wid * 512];
    short* const ldsVB = &lds[28672 + wid * 512];

    #pragma unroll
    for (int i = 0; i < 8; ++i)
        gl_lds16(qsrc + (size_t)i * 32 * DKH, ldsQ + i * 2048);
    gl_lds16(ksrc,        ldsKA);        gl_lds16(ksrc + 2048, ldsKA + 2048);
    gl_lds16(vsrc,        ldsVA);        gl_lds16(vsrc + 32,   ldsVA + 2048);
    gl_lds16(ksrc + 4096, ldsKB);        gl_lds16(ksrc + 6144, ldsKB + 2048);
    gl_lds16(vsrc + 64,   ldsVB);        gl_lds16(vsrc + 96,   ldsVB + 2048);
    __syncthreads();

    bf16x8 bq0[4], bq1[4];
    #pragma unroll
    for (int kc = 0; kc < 4; ++kc) {
        bq0[kc] = *(const bf16x8*)&lds[SWZ(wq0 + l31,      kc * 16 + hi * 8)];
        bq1[kc] = *(const bf16x8*)&lds[SWZ(wq0 + 32 + l31, kc * 16 + hi * 8)];
    }

    f32x16 o00 = (f32x16)0.0f, o01 = (f32x16)0.0f;
    f32x16 o10 = (f32x16)0.0f, o11 = (f32x16)0.0f;
    float l0 = 0.0f, l1 = 0.0f;

    for (int kt = 0; kt < NT64; ++kt) {
        const int KO = (kt & 1) ? 24576 : 16384;
        const int VO = (kt & 1) ? 28672 : 20480;

        f32x16 s0a = (f32x16)0.0f, s0b = (f32x16)0.0f;
        f32x16 s1a = (f32x16)0.0f, s1b = (f32x16)0.0f;
        __builtin_amdgcn_s_setprio(1);
        #pragma unroll
        for (int kc = 0; kc < 4; ++kc) {
            const bf16x8 ak0 = *(const bf16x8*)&lds[KO + SWZ(l31,      kc * 16 + hi * 8)];
            const bf16x8 ak1 = *(const bf16x8*)&lds[KO + SWZ(32 + l31, kc * 16 + hi * 8)];
            s0a = __builtin_amdgcn_mfma_f32_32x32x16_bf16(ak0, bq0[kc], s0a, 0, 0, 0);
            s1a = __builtin_amdgcn_mfma_f32_32x32x16_bf16(ak0, bq1[kc], s1a, 0, 0, 0);
            s0b = __builtin_amdgcn_mfma_f32_32x32x16_bf16(ak1, bq0[kc], s0b, 0, 0, 0);
            s1b = __builtin_amdgcn_mfma_f32_32x32x16_bf16(ak1, bq1[kc], s1b, 0, 0, 0);
        }
        __builtin_amdgcn_s_setprio(0);

        #pragma unroll
        for (int r = 0; r < 16; ++r) s0a[r] = __builtin_amdgcn_exp2f(s0a[r]);
        #pragma unroll
        for (int r = 0; r < 16; ++r) s0b[r] = __builtin_amdgcn_exp2f(s0b[r]);
        #pragma unroll
        for (int r = 0; r < 16; ++r) s1a[r] = __builtin_amdgcn_exp2f(s1a[r]);
        #pragma unroll
        for (int r = 0; r < 16; ++r) s1b[r] = __builtin_amdgcn_exp2f(s1b[r]);
        {
            const float a0 = ((s0a[0]+s0a[1]) + (s0a[2]+s0a[3])) + ((s0a[4]+s0a[5]) + (s0a[6]+s0a[7]));
            const float a1 = ((s0a[8]+s0a[9]) + (s0a[10]+s0a[11])) + ((s0a[12]+s0a[13]) + (s0a[14]+s0a[15]));
            const float a2 = ((s0b[0]+s0b[1]) + (s0b[2]+s0b[3])) + ((s0b[4]+s0b[5]) + (s0b[6]+s0b[7]));
            const float a3 = ((s0b[8]+s0b[9]) + (s0b[10]+s0b[11])) + ((s0b[12]+s0b[13]) + (s0b[14]+s0b[15]));
            l0 += (a0 + a1) + (a2 + a3);
            const float c0 = ((s1a[0]+s1a[1]) + (s1a[2]+s1a[3])) + ((s1a[4]+s1a[5]) + (s1a[6]+s1a[7]));
            const float c1 = ((s1a[8]+s1a[9]) + (s1a[10]+s1a[11])) + ((s1a[12]+s1a[13]) + (s1a[14]+s1a[15]));
            const float c2 = ((s1b[0]+s1b[1]) + (s1b[2]+s1b[3])) + ((s1b[4]+s1b[5]) + (s1b[6]+s1b[7]));
            const float c3 = ((s1b[8]+s1b[9]) + (s1b[10]+s1b[11])) + ((s1b[12]+s1b[13]) + (s1b[14]+s1b[15]));
            l1 += (c0 + c1) + (c2 + c3);
        }

        // --- k-block a: pack (T12) + PV on V subtile 0 ---
        {
            bf16x8 bp00, bp01, bp10, bp11;
            {
                unsigned a0 = pk2(s0a[0], s0a[1]),  b0 = pk2(s0a[4],  s0a[5]);
                unsigned a1 = pk2(s0a[2], s0a[3]),  b1 = pk2(s0a[6],  s0a[7]);
                asm("v_permlane32_swap_b32 %0, %1" : "+v"(a0), "+v"(b0));
                asm("v_permlane32_swap_b32 %0, %1" : "+v"(a1), "+v"(b1));
                bp00 = mk8(a0, a1, b0, b1);
                unsigned a2 = pk2(s0a[8], s0a[9]),   b2 = pk2(s0a[12], s0a[13]);
                unsigned a3 = pk2(s0a[10], s0a[11]), b3 = pk2(s0a[14], s0a[15]);
                asm("v_permlane32_swap_b32 %0, %1" : "+v"(a2), "+v"(b2));
                asm("v_permlane32_swap_b32 %0, %1" : "+v"(a3), "+v"(b3));
                bp01 = mk8(a2, a3, b2, b3);
            }
            {
                unsigned a0 = pk2(s1a[0], s1a[1]),  b0 = pk2(s1a[4],  s1a[5]);
                unsigned a1 = pk2(s1a[2], s1a[3]),  b1 = pk2(s1a[6],  s1a[7]);
                asm("v_permlane32_swap_b32 %0, %1" : "+v"(a0), "+v"(b0));
                asm("v_permlane32_swap_b32 %0, %1" : "+v"(a1), "+v"(b1));
                bp10 = mk8(a0, a1, b0, b1);
                unsigned a2 = pk2(s1a[8], s1a[9]),   b2 = pk2(s1a[12], s1a[13]);
                unsigned a3 = pk2(s1a[10], s1a[11]), b3 = pk2(s1a[14], s1a[15]);
                asm("v_permlane32_swap_b32 %0, %1" : "+v"(a2), "+v"(b2));
                asm("v_permlane32_swap_b32 %0, %1" : "+v"(a3), "+v"(b3));
                bp11 = mk8(a2, a3, b2, b3);
            }
            __builtin_amdgcn_s_setprio(1);
            const bf16x8 avA0 = *(const bf16x8*)&lds[VO + SWZV(l31,      hi * 8)];
            const bf16x8 avA1 = *(const bf16x8*)&lds[VO + SWZV(32 + l31, hi * 8)];
            o00 = __builtin_amdgcn_mfma_f32_32x32x16_bf16(avA0, bp00, o00, 0, 0, 0);
            o01 = __builtin_amdgcn_mfma_f32_32x32x16_bf16(avA1, bp00, o01, 0, 0, 0);
            o10 = __builtin_amdgcn_mfma_f32_32x32x16_bf16(avA0, bp10, o10, 0, 0, 0);
            o11 = __builtin_amdgcn_mfma_f32_32x32x16_bf16(avA1, bp10, o11, 0, 0, 0);
            const bf16x8 avB0 = *(const bf16x8*)&lds[VO + SWZV(l31,      16 + hi * 8)];
            const bf16x8 avB1 = *(const bf16x8*)&lds[VO + SWZV(32 + l31, 16 + hi * 8)];
            o00 = __builtin_amdgcn_mfma_f32_32x32x16_bf16(avB0, bp01, o00, 0, 0, 0);
            o01 = __builtin_amdgcn_mfma_f32_32x32x16_bf16(avB1, bp01, o01, 0, 0, 0);
            o10 = __builtin_amdgcn_mfma_f32_32x32x16_bf16(avB0, bp11, o10, 0, 0, 0);
            o11 = __builtin_amdgcn_mfma_f32_32x32x16_bf16(avB1, bp11, o11, 0, 0, 0);
            __builtin_amdgcn_s_setprio(0);
        }

        // --- k-block b: pack + PV on V subtile 1 (VO + 2048) ---
        {
            bf16x8 bp00, bp01, bp10, bp11;
            {
                unsigned a0 = pk2(s0b[0], s0b[1]),  b0 = pk2(s0b[4],  s0b[5]);
                unsigned a1 = pk2(s0b[2], s0b[3]),  b1 = pk2(s0b[6],  s0b[7]);
                asm("v_permlane32_swap_b32 %0, %1" : "+v"(a0), "+v"(b0));
                asm("v_permlane32_swap_b32 %0, %1" : "+v"(a1), "+v"(b1));
                bp00 = mk8(a0, a1, b0, b1);
                unsigned a2 = pk2(s0b[8], s0b[9]),   b2 = pk2(s0b[12], s0b[13]);
                unsigned a3 = pk2(s0b[10], s0b[11]), b3 = pk2(s0b[14], s0b[15]);
                asm("v_permlane32_swap_b32 %0, %1" : "+v"(a2), "+v"(b2));
                asm("v_permlane32_swap_b32 %0, %1" : "+v"(a3), "+v"(b3));
                bp01 = mk8(a2, a3, b2, b3);
            }
            {
                unsigned a0 = pk2(s1b[0], s1b[1]),  b0 = pk2(s1b[4],  s1b[5]);
                unsigned a1 = pk2(s1b[2], s1b[3]),  b1 = pk2(s1b[6],  s1b[7]);
                asm("v_permlane32_swap_b32 %0, %1" : "+v"(a0), "+v"(b0));
                asm("v_permlane32_swap_b32 %0, %1" : "+v"(a1), "+v"(b1));
                bp10 = mk8(a0, a1, b0, b1);
                unsigned a2 = pk2(s1b[8], s1b[9]),   b2 = pk2(s1b[12], s1b[13]);
                unsigned a3 = pk2(s1b[10], s1b[11]), b3 = pk2(s1b[14], s1b[15]);
                asm("v_permlane32_swap_b32 %0, %1" : "+v"(a2), "+v"(b2));
                asm("v_permlane32_swap_b32 %0, %1" : "+v"(a3), "+v"(b3));
                bp11 = mk8(a2, a3, b2, b3);
            }
            __builtin_amdgcn_s_setprio(1);
            const int VO1 = VO + 2048;
            const bf16x8 avA0 = *(const bf16x8*)&lds[VO1 + SWZV(l31,      hi * 8)];
            const bf16x8 avA1 = *(const bf16x8*)&lds[VO1 + SWZV(32 + l31, hi * 8)];
            o00 = __builtin_amdgcn_mfma_f32_32x32x16_bf16(avA0, bp00, o00, 0, 0, 0);
            o01 = __builtin_amdgcn_mfma_f32_32x32x16_bf16(avA1, bp00, o01, 0, 0, 0);
            o10 = __builtin_amdgcn_mfma_f32_32x32x16_bf16(avA0, bp10, o10, 0, 0, 0);
            o11 = __builtin_amdgcn_mfma_f32_32x32x16_bf16(avA1, bp10, o11, 0, 0, 0);
            const bf16x8 avB0 = *(const bf16x8*)&lds[VO1 + SWZV(l31,      16 + hi * 8)];
            const bf16x8 avB1 = *(const bf16x8*)&lds[VO1 + SWZV(32 + l31, 16 + hi * 8)];
            o00 = __builtin_amdgcn_mfma_f32_32x32x16_bf16(avB0, bp01, o00, 0, 0, 0);
            o01 = __builtin_amdgcn_mfma_f32_32x32x16_bf16(avB1, bp01, o01, 0, 0, 0);
            o10 = __builtin_amdgcn_mfma_f32_32x32x16_bf16(avB0, bp11, o10, 0, 0, 0);
            o11 = __builtin_amdgcn_mfma_f32_32x32x16_bf16(avB1, bp11, o11, 0, 0, 0);
            __builtin_amdgcn_s_setprio(0);
        }

        __syncthreads();
        if (kt + 2 < NT64) {
            short* const kdst = (kt & 1) ? ldsKB : ldsKA;
            short* const vdst = (kt & 1) ? ldsVB : ldsVA;
            const size_t ko = (size_t)(kt + 2) * 4096;
            const int    vo = (kt + 2) * 64;
            gl_lds16(ksrc + ko,        kdst);
            gl_lds16(ksrc + ko + 2048, kdst + 2048);
            gl_lds16(vsrc + vo,        vdst);
            gl_lds16(vsrc + vo + 32,   vdst + 2048);
        }
    }

    #pragma unroll
    for (int qb = 0; qb < 2; ++qb) {
        const float lr = qb ? l1 : l0;
        const f32x16 oa = qb ? o10 : o00;
        const f32x16 ob = qb ? o11 : o01;
        const float lt = lr + __shfl_xor(lr, 32);
        const float inv = 1.0f / lt;
        const int q = q0 + wq0 + qb * 32 + l31;
        short* Op = Ab + ((size_t)b * SEQ + q) * D_MODEL + h * DKH;
        #pragma unroll
        for (int rr = 0; rr < 4; ++rr) {
            bf16x4 ov;
            ov[0] = (__bf16)(oa[rr*4+0] * inv); ov[1] = (__bf16)(oa[rr*4+1] * inv);
            ov[2] = (__bf16)(oa[rr*4+2] * inv); ov[3] = (__bf16)(oa[rr*4+3] * inv);
            *(bf16x4*)&Op[rr * 8 + hi * 4] = ov;
            bf16x4 ow;
            ow[0] = (__bf16)(ob[rr*4+0] * inv); ow[1] = (__bf16)(ob[rr*4+1] * inv);
            ow[2] = (__bf16)(ob[rr*4+2] * inv); ow[3] = (__bf16)(ob[rr*4+3] * inv);
            *(bf16x4*)&Op[32 + rr * 8 + hi * 4] = ow;
        }
    }
}

extern "C" void kernel_launch(void* const* d_in, const int* in_sizes, int n_in,
                              void* d_out, int out_size, void* d_ws, size_t ws_size,
                              hipStream_t stream) {
    const float* q_in = (const float*)d_in[0];
    const float* k_in = (const float*)d_in[1];
    const float* v_in = (const float*)d_in[2];
    const float* w_q  = (const float*)d_in[3];
    const float* b_q  = (const float*)d_in[4];
    const float* w_k  = (const float*)d_in[5];
    const float* b_k  = (const float*)d_in[6];
    const float* w_v  = (const float*)d_in[7];
    const float* b_v  = (const float*)d_in[8];
    const float* w_o  = (const float*)d_in[9];
    const float* b_o  = (const float*)d_in[10];
    float* out = (float*)d_out;

    short* ws = (short*)d_ws;
    short* Wq = ws;                   // bf16 weights
    short* Wk = Wq + WSZ;
    short* Wv = Wk + WSZ;
    short* Wo = Wv + WSZ;
    short* Qb = ws + 4 * WSZ;         // (B,H,S,64) bf16, pre-scaled
    short* Kb = Qb + BSD;             // (B,H,S,64) bf16
    short* Vt = Kb + BSD;             // (B,H,64,S) bf16 -- direct from gemm
    short* Ab = Vt + BSD;             // (B,S,D) bf16 attn output

    dim3 blk(256);

    CvtPtrs cp;
    cp.src[0] = w_q; cp.dst[0] = Wq;
    cp.src[1] = w_k; cp.dst[1] = Wk;
    cp.src[2] = w_v; cp.dst[2] = Wv;
    cp.src[3] = w_o; cp.dst[3] = Wo;
    cvt_w<<<dim3(4 * 512), blk, 0, stream>>>(cp);

    QkvArgs qa;
    qa.A[0] = q_in; qa.W[0] = Wq; qa.bias[0] = b_q; qa.out[0] = Qb; qa.scale[0] = 0.125f * LOG2E; qa.omode[0] = 1;
    qa.A[1] = k_in; qa.W[1] = Wk; qa.bias[1] = b_k; qa.out[1] = Kb; qa.scale[1] = 1.0f;           qa.omode[1] = 1;
    qa.A[2] = v_in; qa.W[2] = Wv; qa.bias[2] = b_v; qa.out[2] = Vt; qa.scale[2] = 1.0f;           qa.omode[2] = 2;
    gemm_qkv<<<dim3(D_MODEL / 128, MROWS / 128, 3), blk, 0, stream>>>(qa);

    attn_mfma<<<dim3(SEQ / 256, BATCH * NHEADS), blk, 0, stream>>>(Qb, Kb, Vt, Ab);

    gemm_out<<<dim3(D_MODEL / 128, MROWS / 128), blk, 0, stream>>>(Ab, Wo, b_o, out);
}